// Round 14
// baseline (77.092 us; speedup 1.0000x reference)
//
#include <hip/hip_runtime.h>
#include <math.h>

// Problem constants: b=2, h=4, n_tot=585, d=128, n=512, k=8
// Levels: L0 rows [0,512), L1 [512,576), L2 [576,584), L3 {584}
// Lane layout: s = lane>>3 (key slot 0..7), c = lane&7 (dim chunk of 16)
//
// Masked-entry algebra (exact, R8-proven); single-launch closure (R13-proven).
// R14: K/V staged in LDS as packed bf16 pairs — halves ds_read count per
// row-visit (2x b128 instead of 4x), halves LDS footprint (94->48 KB).
// Bank layout: row stride 272 B = 68 words ≡ 4 (mod 32); c-offsets 8 words
// -> all 32 banks hit exactly 8x per b128 instruction (even, conflict-free).
#define D 128
#define NTOT 585
#define SCALE 0.08838834764831845f  // 1/sqrt(128)
#define THIRD 0.33333333333333333f
#define LROWU 68                    // uints per LDS row (136 bf16 = 272 B)

// ---- bf16 pair pack/unpack (RNE pack; unpack = shift-reinterpret) ----------
__device__ __forceinline__ unsigned int packbf2(float a, float b) {
    unsigned int ua = __float_as_uint(a);
    unsigned int ub = __float_as_uint(b);
    ua += 0x7fffu + ((ua >> 16) & 1u);
    ub += 0x7fffu + ((ub >> 16) & 1u);
    return (ua >> 16) | (ub & 0xffff0000u);
}
__device__ __forceinline__ float bflo(unsigned int u) { return __uint_as_float(u << 16); }
__device__ __forceinline__ float bfhi(unsigned int u) { return __uint_as_float(u & 0xffff0000u); }

__device__ __forceinline__ float rsum_c(float v) {  // sum over c (strides 1,2,4)
    v += __shfl_xor(v, 1, 64);
    v += __shfl_xor(v, 2, 64);
    v += __shfl_xor(v, 4, 64);
    return v;
}
__device__ __forceinline__ float rsum_s(float v) {  // sum over s (strides 8,16,32)
    v += __shfl_xor(v, 8, 64);
    v += __shfl_xor(v, 16, 64);
    v += __shfl_xor(v, 32, 64);
    return v;
}
__device__ __forceinline__ float rmax_s(float v) {
    v = fmaxf(v, __shfl_xor(v, 8, 64));
    v = fmaxf(v, __shfl_xor(v, 16, 64));
    v = fmaxf(v, __shfl_xor(v, 32, 64));
    return v;
}

// 16-dim partial dot vs a bf16 LDS row (2x uint4 = 8 packed pairs)
__device__ __forceinline__ float dot16b(const float4 q[4],
                                        const unsigned int* __restrict__ rowU, int c) {
    const uint4* p = (const uint4*)(rowU + (c << 3));
    uint4 a = p[0], b = p[1];
    float d0 = q[0].x * bflo(a.x) + q[0].y * bfhi(a.x)
             + q[0].z * bflo(a.y) + q[0].w * bfhi(a.y);
    float d1 = q[1].x * bflo(a.z) + q[1].y * bfhi(a.z)
             + q[1].z * bflo(a.w) + q[1].w * bfhi(a.w);
    float d2 = q[2].x * bflo(b.x) + q[2].y * bfhi(b.x)
             + q[2].z * bflo(b.y) + q[2].w * bfhi(b.y);
    float d3 = q[3].x * bflo(b.z) + q[3].y * bfhi(b.z)
             + q[3].z * bflo(b.w) + q[3].w * bfhi(b.w);
    return (d0 + d1) + (d2 + d3);
}
// acc += w * bf16-LDS-row chunk
__device__ __forceinline__ void vaccb(float w, const unsigned int* __restrict__ rowU,
                                      int c, float4 acc[4]) {
    const uint4* p = (const uint4*)(rowU + (c << 3));
    uint4 a = p[0], b = p[1];
    acc[0].x += w * bflo(a.x); acc[0].y += w * bfhi(a.x);
    acc[0].z += w * bflo(a.y); acc[0].w += w * bfhi(a.y);
    acc[1].x += w * bflo(a.z); acc[1].y += w * bfhi(a.z);
    acc[1].z += w * bflo(a.w); acc[1].w += w * bfhi(a.w);
    acc[2].x += w * bflo(b.x); acc[2].y += w * bfhi(b.x);
    acc[2].z += w * bflo(b.y); acc[2].w += w * bfhi(b.y);
    acc[3].x += w * bflo(b.z); acc[3].y += w * bfhi(b.z);
    acc[3].z += w * bflo(b.w); acc[3].w += w * bfhi(b.w);
}
__device__ __forceinline__ void vacc_reg(float w, const float4 vv[4], float4 acc[4]) {
#pragma unroll
    for (int u = 0; u < 4; ++u) {
        acc[u].x += w * vv[u].x; acc[u].y += w * vv[u].y;
        acc[u].z += w * vv[u].z; acc[u].w += w * vv[u].w;
    }
}
__device__ __forceinline__ void loadq(const float* __restrict__ qrow, int c, float4 q[4]) {
    const float4* qp = (const float4*)(qrow + (c << 4));
#pragma unroll
    for (int u = 0; u < 4; ++u) q[u] = qp[u];
}
__device__ __forceinline__ void butterfly_acc(float4 acc[4]) {
#pragma unroll
    for (int u = 0; u < 4; ++u) {
        acc[u].x = rsum_s(acc[u].x);
        acc[u].y = rsum_s(acc[u].y);
        acc[u].z = rsum_s(acc[u].z);
        acc[u].w = rsum_s(acc[u].w);
    }
}

// anc softmax for an L0-style query (g pass rows from LDS anc slots [16,80),
// (64-g) masked copies of lg0 with value slot 80): R9/R13-exact structure.
__device__ __forceinline__ void anc_l0(const float4 q4[4], int g, int s, int c,
                                       const unsigned int* __restrict__ KsU,
                                       const unsigned int* __restrict__ VsU,
                                       float lg0, float4 acc[4]) {
    float lgA[8];
    float mloc = lg0;
#pragma unroll
    for (int R = 0; R < 4; ++R) {
        if (16 * R < g) {                       // wave-uniform guard
#pragma unroll
            for (int rr = 0; rr < 2; ++rr) {
                const int r = 2 * R + rr;
                const int j = 8 * r + s;
                float lg = -1e30f;
                if (j < g)                       // octet-uniform
                    lg = rsum_c(dot16b(q4, KsU + (16 + j) * LROWU, c)) * SCALE;
                lgA[r] = lg;
                mloc = fmaxf(mloc, lg);
            }
        } else { lgA[2 * R] = -1e30f; lgA[2 * R + 1] = -1e30f; }
    }
    const float m = rmax_s(mloc);
    const float e0 = __expf(lg0 - m);
    float zp = (s == 0) ? (float)(64 - g) * e0 : 0.f;
    float eA[8];
#pragma unroll
    for (int R = 0; R < 4; ++R) {
        if (16 * R < g) {
#pragma unroll
            for (int rr = 0; rr < 2; ++rr) {
                const int r = 2 * R + rr;
                eA[r] = (lgA[r] > -1e29f) ? __expf(lgA[r] - m) : 0.f;
                zp += eA[r];
            }
        }
    }
    const float inv = 1.f / rsum_s(zp);
#pragma unroll
    for (int R = 0; R < 4; ++R) {
        if (16 * R < g) {
#pragma unroll
            for (int rr = 0; rr < 2; ++rr) {
                const int r = 2 * R + rr;
                const int j = 8 * r + s;
                if (j < g) vaccb(eA[r] * inv, VsU + (16 + j) * LROWU, c, acc);
            }
        }
    }
    if (s == 0) vaccb((float)(64 - g) * e0 * inv, VsU + 80 * LROWU, c, acc);
}

// ================== single fused kernel: L0 + L1 + L2 + L3 ===================
// 256 blocks (8 bh x 32) x 1024 threads = 16 waves.
// LDS rows (bf16): [0,16) = global qb0..qb0+15; [16,80) = 512..575; 80 = row 0;
// [81,89) = 576..583.  2 x 89 x 68 uints = 48.4 KB.
__global__ __launch_bounds__(1024) void sequoia_fused(const float* __restrict__ Q,
                                                      const float* __restrict__ K,
                                                      const float* __restrict__ V,
                                                      float* __restrict__ Out) {
    __shared__ unsigned int KsU[89 * LROWU];
    __shared__ unsigned int VsU[89 * LROWU];
    const int tid = threadIdx.x;
    const int lane = tid & 63;
    const int s = lane >> 3, c = lane & 7;
    const int bh = blockIdx.x >> 5;
    const int qb0 = (blockIdx.x & 31) << 4;  // first L0 query of this block
    const float* Qb = Q + (size_t)bh * NTOT * D;
    const float* Kb = K + (size_t)bh * NTOT * D;
    const float* Vb = V + (size_t)bh * NTOT * D;
    float* Ob = Out + (size_t)bh * NTOT * D;

    // ---- stage 89 K rows + 89 V rows as packed bf16 pairs ----
    for (int t = tid; t < 89 * 32; t += 1024) {
        const int row = t >> 5, col = (t & 31) << 2;   // col in floats
        int src;
        if (row < 16)       src = qb0 + row;
        else if (row < 80)  src = 512 + row - 16;
        else if (row == 80) src = 0;
        else                src = 576 + (row - 81);
        const float4 kv = *(const float4*)(Kb + (size_t)src * D + col);
        const float4 vv = *(const float4*)(Vb + (size_t)src * D + col);
        *(uint2*)(KsU + row * LROWU + (col >> 1)) =
            make_uint2(packbf2(kv.x, kv.y), packbf2(kv.z, kv.w));
        *(uint2*)(VsU + row * LROWU + (col >> 1)) =
            make_uint2(packbf2(vv.x, vv.y), packbf2(vv.z, vv.w));
    }
    __syncthreads();

    const int w = tid >> 6;       // wave 0..15

    // ========================= Phase L0 (all waves) ==========================
    {
        const int i = qb0 + w;        // this wave's L0 query
        const int sl = i & 7;
        const int g = i >> 3;
        const int sibbase = w & 8;    // LDS sib row base for this wave's group

        float4 q4[4];
        loadq(Qb + (size_t)i * D, c, q4);
        float4 acc[4] = {{0,0,0,0},{0,0,0,0},{0,0,0,0},{0,0,0,0}};
        const float lg0 = rsum_c(dot16b(q4, KsU + 80 * LROWU, c)) * SCALE;
        // sib
        {
            float lg = -1e30f;
            if (s <= sl)
                lg = rsum_c(dot16b(q4, KsU + (sibbase + s) * LROWU, c)) * SCALE;
            const float m = fmaxf(rmax_s(lg), lg0);
            const float e = (s <= sl) ? __expf(lg - m) : 0.f;
            const float e0 = __expf(lg0 - m);
            float zp = e;
            if (s == 0) zp += (float)(7 - sl) * e0;
            const float inv = 1.f / rsum_s(zp);
            if (s <= sl) vaccb(e * inv, VsU + (sibbase + s) * LROWU, c, acc);
            if (s == 0 && sl < 7) vaccb((float)(7 - sl) * e0 * inv, VsU + 80 * LROWU, c, acc);
        }
        // anc
        anc_l0(q4, g, s, c, KsU, VsU, lg0, acc);
        butterfly_acc(acc);
        if (s == 0) {
            float4* orow = (float4*)(Ob + (size_t)i * D + (c << 4));
#pragma unroll
            for (int u = 0; u < 4; ++u)
                orow[u] = make_float4(acc[u].x * THIRD, acc[u].y * THIRD,
                                      acc[u].z * THIRD, acc[u].w * THIRD);
        }
    }

    // ================= Phase chain (waves 0..1): L1 (+L2,+L3) ================
    if (w < 2) {
        const int ci = (qb0 >> 3) + w;   // L1 query index 0..63 (8*ci = qb0+8w)

        // v0n = updated row 0 = (2/3)*V[0] (analytic, unpacked from LDS)
        float4 v0n[4];
        {
            const uint4* vp = (const uint4*)(VsU + 80 * LROWU + (c << 3));
            uint4 a = vp[0], b = vp[1];
            const float k = 2.f * THIRD;
            v0n[0] = make_float4(bflo(a.x) * k, bfhi(a.x) * k, bflo(a.y) * k, bfhi(a.y) * k);
            v0n[1] = make_float4(bflo(a.z) * k, bfhi(a.z) * k, bflo(a.w) * k, bfhi(a.w) * k);
            v0n[2] = make_float4(bflo(b.x) * k, bfhi(b.x) * k, bflo(b.y) * k, bfhi(b.y) * k);
            v0n[3] = make_float4(bflo(b.z) * k, bfhi(b.z) * k, bflo(b.w) * k, bfhi(b.w) * k);
        }

        // ---- o0 = updated row 8*ci, recomputed ALL-LDS (sl=0 shortcut) ----
        float4 o0[4];
        if (ci == 0) {
#pragma unroll
            for (int u = 0; u < 4; ++u) o0[u] = v0n[u];
        } else {
            float4 q0[4];
            loadq(Qb + (size_t)(8 * ci) * D, c, q0);
            float4 acc[4] = {{0,0,0,0},{0,0,0,0},{0,0,0,0},{0,0,0,0}};
            const float lg0 = rsum_c(dot16b(q0, KsU + 80 * LROWU, c)) * SCALE;
            // sib (sl=0): pass row 8*ci = LDS sib slot 8w
            {
                float lg = -1e30f;
                if (s == 0)
                    lg = rsum_c(dot16b(q0, KsU + (8 * w) * LROWU, c)) * SCALE;
                const float m = fmaxf(rmax_s(lg), lg0);
                const float e = (s == 0) ? __expf(lg - m) : 0.f;
                const float e0 = __expf(lg0 - m);
                float zp = e;
                if (s == 0) zp += 7.f * e0;
                const float inv = 1.f / rsum_s(zp);
                if (s == 0) {
                    vaccb(e * inv, VsU + (8 * w) * LROWU, c, acc);
                    vaccb(7.f * e0 * inv, VsU + 80 * LROWU, c, acc);
                }
            }
            anc_l0(q0, ci, s, c, KsU, VsU, lg0, acc);  // g = ci
            butterfly_acc(acc);
#pragma unroll
            for (int u = 0; u < 4; ++u)
                o0[u] = make_float4(acc[u].x * THIRD, acc[u].y * THIRD,
                                    acc[u].z * THIRD, acc[u].w * THIRD);
        }

        // ------------------------------ Level 1 ------------------------------
        float4 o1[4];
        {
            float4 q1[4];
            loadq(Qb + (size_t)(512 + ci) * D, c, q1);
            float4 acc[4] = {{0,0,0,0},{0,0,0,0},{0,0,0,0},{0,0,0,0}};
            const float lg0q = rsum_c(dot16b(q1, KsU + 80 * LROWU, c)) * SCALE;
            const int sl1 = ci & 7;
            const int gq = ci >> 3;
            // sib: s<=sl1 -> LDS anc slot 16+(ci&~7)+s (V original); masked -> v0n
            {
                const int slot = 16 + (ci & ~7) + s;
                float lg = -1e30f;
                if (s <= sl1)
                    lg = rsum_c(dot16b(q1, KsU + slot * LROWU, c)) * SCALE;
                const float m = fmaxf(rmax_s(lg), lg0q);
                const float e = (s <= sl1) ? __expf(lg - m) : 0.f;
                const float e0 = __expf(lg0q - m);
                float zp = e;
                if (s == 0) zp += (float)(7 - sl1) * e0;
                const float inv = 1.f / rsum_s(zp);
                if (s <= sl1) vaccb(e * inv, VsU + slot * LROWU, c, acc);
                if (s == 0 && sl1 < 7) vacc_reg((float)(7 - sl1) * e0 * inv, v0n, acc);
            }
            // anc: s<gq -> LDS slot 81+s (V original); masked -> v0n
            {
                float lg = -1e30f;
                if (s < gq)
                    lg = rsum_c(dot16b(q1, KsU + (81 + s) * LROWU, c)) * SCALE;
                const float m = fmaxf(rmax_s(lg), lg0q);
                const float e = (s < gq) ? __expf(lg - m) : 0.f;
                const float e0 = __expf(lg0q - m);
                float zp = e;
                if (s == 0) zp += (float)(8 - gq) * e0;
                const float inv = 1.f / rsum_s(zp);
                if (s < gq) vaccb(e * inv, VsU + (81 + s) * LROWU, c, acc);
                if (s == 0) vacc_reg((float)(8 - gq) * e0 * inv, v0n, acc);  // gq<=7
            }
            // chi: s==0 -> (K row 8*ci = LDS sib slot 8w, o0 regs); masked -> v0n
            {
                float lg = -1e30f;
                if (s == 0)
                    lg = rsum_c(dot16b(q1, KsU + (8 * w) * LROWU, c)) * SCALE;
                const float m = fmaxf(rmax_s(lg), lg0q);
                const float e = (s == 0) ? __expf(lg - m) : 0.f;
                const float e0 = __expf(lg0q - m);
                const float zp = (s == 0) ? (e + 7.f * e0) : 0.f;
                const float inv = 1.f / rsum_s(zp);
                if (s == 0) {
                    vacc_reg(e * inv, o0, acc);
                    vacc_reg(7.f * e0 * inv, v0n, acc);
                }
            }
            butterfly_acc(acc);
#pragma unroll
            for (int u = 0; u < 4; ++u)
                o1[u] = make_float4(acc[u].x * THIRD, acc[u].y * THIRD,
                                    acc[u].z * THIRD, acc[u].w * THIRD);
            if (s == 0) {
                float4* orow = (float4*)(Ob + (size_t)(512 + ci) * D + (c << 4));
#pragma unroll
                for (int u = 0; u < 4; ++u) orow[u] = o1[u];
            }
        }

        // ---------------- Level 2 (blocks qb0%64==0, wave 0) -----------------
        if (w == 0 && (ci & 7) == 0) {
            const int j = ci >> 3;   // == qb0/64, 0..7
            float4 q2[4];
            loadq(Qb + (size_t)(576 + j) * D, c, q2);
            float4 acc[4] = {{0,0,0,0},{0,0,0,0},{0,0,0,0},{0,0,0,0}};
            const float lg0q = rsum_c(dot16b(q2, KsU + 80 * LROWU, c)) * SCALE;
            // sib: s<=j -> LDS slot 81+s (V original); masked -> v0n
            {
                float lg = -1e30f;
                if (s <= j)
                    lg = rsum_c(dot16b(q2, KsU + (81 + s) * LROWU, c)) * SCALE;
                const float m = fmaxf(rmax_s(lg), lg0q);
                const float e = (s <= j) ? __expf(lg - m) : 0.f;
                const float e0 = __expf(lg0q - m);
                float zp = e;
                if (s == 0) zp += (float)(7 - j) * e0;
                const float inv = 1.f / rsum_s(zp);
                if (s <= j) vaccb(e * inv, VsU + (81 + s) * LROWU, c, acc);
                if (s == 0 && j < 7) vacc_reg((float)(7 - j) * e0 * inv, v0n, acc);
            }
            // chi: s==0 -> (K row 512+8j = LDS anc slot 16+8j, o1 regs); masked -> v0n
            {
                float lg = -1e30f;
                if (s == 0)
                    lg = rsum_c(dot16b(q2, KsU + (16 + 8 * j) * LROWU, c)) * SCALE;
                const float m = fmaxf(rmax_s(lg), lg0q);
                const float e = (s == 0) ? __expf(lg - m) : 0.f;
                const float e0 = __expf(lg0q - m);
                const float zp = (s == 0) ? (e + 7.f * e0) : 0.f;
                const float inv = 1.f / rsum_s(zp);
                if (s == 0) {
                    vacc_reg(e * inv, o1, acc);
                    vacc_reg(7.f * e0 * inv, v0n, acc);
                }
            }
            butterfly_acc(acc);
            // anc: single always-masked entry -> weight exactly 1 on v0n
            float4 o2[4];
#pragma unroll
            for (int u = 0; u < 4; ++u)
                o2[u] = make_float4((acc[u].x + v0n[u].x) * THIRD,
                                    (acc[u].y + v0n[u].y) * THIRD,
                                    (acc[u].z + v0n[u].z) * THIRD,
                                    (acc[u].w + v0n[u].w) * THIRD);
            if (s == 0) {
                float4* orow = (float4*)(Ob + (size_t)(576 + j) * D + (c << 4));
#pragma unroll
                for (int u = 0; u < 4; ++u) orow[u] = o2[u];
            }

            // ------------------- Level 3 (block qb0 == 0) --------------------
            if (j == 0) {
                float4 q3[4];
                loadq(Qb + (size_t)584 * D, c, q3);
                const float lg0r = rsum_c(dot16b(q3, KsU + 80 * LROWU, c)) * SCALE;
                // chi: s==0 -> (K row 576 = LDS slot 81, o2 regs); masked -> v0n
                float lg = -1e30f;
                if (s == 0)
                    lg = rsum_c(dot16b(q3, KsU + 81 * LROWU, c)) * SCALE;
                const float m = fmaxf(rmax_s(lg), lg0r);
                const float e = (s == 0) ? __expf(lg - m) : 0.f;
                const float e0 = __expf(lg0r - m);
                const float zp = (s == 0) ? (e + 7.f * e0) : 0.f;
                const float inv = 1.f / rsum_s(zp);
                float4 acc3[4] = {{0,0,0,0},{0,0,0,0},{0,0,0,0},{0,0,0,0}};
                if (s == 0) {
                    vacc_reg(e * inv, o2, acc3);
                    vacc_reg(7.f * e0 * inv, v0n, acc3);
                }
                butterfly_acc(acc3);
                // sib: 8 identical entries on row 584 -> ORIGINAL V[584] (fp32 global)
                if (s == 0) {
                    const float4* v584 = (const float4*)(Vb + (size_t)584 * D + (c << 4));
                    float4* orow = (float4*)(Ob + (size_t)584 * D + (c << 4));
#pragma unroll
                    for (int u = 0; u < 4; ++u) {
                        float4 bb = v584[u];
                        orow[u] = make_float4((acc3[u].x + bb.x) * THIRD,
                                              (acc3[u].y + bb.y) * THIRD,
                                              (acc3[u].z + bb.z) * THIRD,
                                              (acc3[u].w + bb.w) * THIRD);
                    }
                }
            }
        }
    }
}

extern "C" void kernel_launch(void* const* d_in, const int* in_sizes, int n_in,
                              void* d_out, int out_size, void* d_ws, size_t ws_size,
                              hipStream_t stream) {
    const float* Q = (const float*)d_in[0];
    const float* K = (const float*)d_in[1];
    const float* V = (const float*)d_in[2];
    float* Out = (float*)d_out;
    // ONE launch: 256 blocks x 1024 threads; K/V staged as bf16 in LDS
    // (48.4 KB); chain (L1/L2/L3) rides in-block with no cross-block deps.
    hipLaunchKernelGGL(sequoia_fused, dim3(256), dim3(1024), 0, stream, Q, K, V, Out);
}